// Round 1
// baseline (67.384 us; speedup 1.0000x reference)
//
#include <hip/hip_runtime.h>
#include <stdint.h>

// Workspace layout:
//   xm: uint32 [r=8][s=16][b=512][w=4]          = 1 MB    (x bit-planes)
//   wm: uint32 [p=2][j=128][r=8][sl=8][8]       = 512 KB  (hi[4],lo[4] per slice)
//   qp: float  [rp=16][j=128][b=512]            = 4 MB    (per row-tile/path quantized partials)
#define XM_BYTES (8u*16u*512u*4u*4u)
#define WM_BYTES (2u*128u*8u*8u*8u*4u)

__global__ __launch_bounds__(256) void pack_x_k(const float* __restrict__ x, uint32_t* __restrict__ xm){
    int wave = blockIdx.x*4 + (threadIdx.x >> 6);
    int lane = threadIdx.x & 63;
    int b  = wave >> 4;       // 512
    int kg = wave & 15;       // 16 groups of 64 k
    int k  = kg*64 + lane;
    float xf = x[b*1024 + k];
    float v = rintf(xf * 4096.0f);
    v = fminf(fmaxf(v, -32768.0f), 32767.0f);
    int xi = (int)v;
    uint32_t u = (uint32_t)xi & 0xFFFFu;   // two's-complement wrap
    int r = kg >> 1, half = kg & 1;
    #pragma unroll
    for (int s = 0; s < 16; ++s){
        unsigned long long m = __ballot((u >> s) & 1u);
        if (lane == 0){
            uint32_t* dst = xm + ((r*16 + s)*512 + b)*4 + half*2;
            dst[0] = (uint32_t)m;
            dst[1] = (uint32_t)(m >> 32);
        }
    }
}

__global__ __launch_bounds__(256) void pack_w_k(const float* __restrict__ w, uint32_t* __restrict__ wm){
    int wave = blockIdx.x*4 + (threadIdx.x >> 6);
    int lane = threadIdx.x & 63;
    int j  = wave >> 4;       // 128
    int kg = wave & 15;
    int k  = kg*64 + lane;
    float wf = w[j*1024 + k];
    int r = kg >> 1, half = kg & 1;
    for (int p = 0; p < 2; ++p){
        float val = p ? fmaxf(-wf, 0.0f) : fmaxf(wf, 0.0f);
        float q = rintf(val * 4096.0f);
        q = fminf(q, 65535.0f);
        uint32_t u = (uint32_t)q;
        #pragma unroll
        for (int sl = 0; sl < 8; ++sl){
            uint32_t v2 = (u >> (2*(7 - sl))) & 3u;
            unsigned long long mh = __ballot(v2 >> 1);
            unsigned long long ml = __ballot(v2 & 1u);
            if (lane == 0){
                uint32_t* base = wm + ((((p*128 + j)*8 + r)*8 + sl)*8);
                base[half*2 + 0]     = (uint32_t)mh;
                base[half*2 + 1]     = (uint32_t)(mh >> 32);
                base[4 + half*2 + 0] = (uint32_t)ml;
                base[4 + half*2 + 1] = (uint32_t)(ml >> 32);
            }
        }
    }
}

__global__ __launch_bounds__(256) void mvm_main_k(const uint32_t* __restrict__ xm,
                                                  const uint32_t* __restrict__ wm,
                                                  float* __restrict__ qp){
    const int lane = threadIdx.x & 63;
    const int j  = blockIdx.x*4 + (threadIdx.x >> 6);
    const int rp = blockIdx.y;              // r*2 + p
    const int r  = rp >> 1, p = rp & 1;
    const int b  = blockIdx.z*64 + lane;

    // Load the 16 stream bit-planes (4 words each) for this (b, r): coalesced dwordx4.
    uint32_t xs[64];
    const uint32_t* xb = xm + ((r*16)*512 + b)*4;
    #pragma unroll
    for (int s = 0; s < 16; ++s){
        const uint4 v4 = *reinterpret_cast<const uint4*>(xb + s*512*4);
        xs[s*4+0] = v4.x; xs[s*4+1] = v4.y; xs[s*4+2] = v4.z; xs[s*4+3] = v4.w;
    }

    const int wbase = __builtin_amdgcn_readfirstlane(((((p*128 + j)*8 + r)*8))*8);
    const float C1   = (float)(511.0/384.0);   // 1/step
    const float STEP = (float)(384.0/511.0);
    float acc = 0.0f;

    for (int sl = 0; sl < 8; ++sl){
        const uint32_t h0 = wm[wbase + sl*8 + 0];
        const uint32_t h1 = wm[wbase + sl*8 + 1];
        const uint32_t h2 = wm[wbase + sl*8 + 2];
        const uint32_t h3 = wm[wbase + sl*8 + 3];
        const uint32_t l0 = wm[wbase + sl*8 + 4];
        const uint32_t l1 = wm[wbase + sl*8 + 5];
        const uint32_t l2 = wm[wbase + sl*8 + 6];
        const uint32_t l3 = wm[wbase + sl*8 + 7];
        if (!__any((h0|h1|h2|h3|l0|l1|l2|l3) != 0u)) continue;  // wave-uniform skip of empty slices

        const float base = STEP * (float)(1 << (2*(7 - sl)));   // step * 4^(7-sl), exact pow2 scale
        float a2 = 0.0f;
        #pragma unroll
        for (int s = 0; s < 16; ++s){
            uint32_t chi = __popc(xs[s*4+0] & h0) + __popc(xs[s*4+1] & h1)
                         + __popc(xs[s*4+2] & h2) + __popc(xs[s*4+3] & h3);
            uint32_t clo = __popc(xs[s*4+0] & l0) + __popc(xs[s*4+1] & l1)
                         + __popc(xs[s*4+2] & l2) + __popc(xs[s*4+3] & l3);
            uint32_t c = chi*2u + clo;                 // exact integer count 0..384
            float nf = rintf((float)c * C1);           // == rint(c / step) for all c in [0,384]
            const float sw = (s == 15) ? -32768.0f : (float)(1 << s);  // two's-complement stream weight
            a2 = fmaf(nf, sw, a2);
        }
        acc = fmaf(a2, base, acc);
    }

    float v = acc * (1.0f/16777216.0f);                      // / 2^24
    float q = rintf(v * 4096.0f) * (1.0f/4096.0f);           // accumulator quantization
    q = fminf(fmaxf(q, -8.0f), 8.0f - 1.0f/4096.0f);
    qp[(rp*128 + j)*512 + b] = q;
}

__global__ __launch_bounds__(256) void reduce_k(const float* __restrict__ qp,
                                                const float* __restrict__ bias,
                                                float* __restrict__ out){
    int t = blockIdx.x*256 + threadIdx.x;   // 65536
    int b = t & 511, j = t >> 9;
    float s = 0.0f;
    #pragma unroll
    for (int rp = 0; rp < 16; ++rp){
        float v = qp[(rp*128 + j)*512 + b];
        s += (rp & 1) ? -v : v;             // exact: all multiples of 2^-12, |sum| < 2^7
    }
    out[b*128 + j] = s + bias[j];
}

extern "C" void kernel_launch(void* const* d_in, const int* in_sizes, int n_in,
                              void* d_out, int out_size, void* d_ws, size_t ws_size,
                              hipStream_t stream){
    const float* x    = (const float*)d_in[0];
    const float* w    = (const float*)d_in[1];
    const float* bias = (const float*)d_in[2];
    float* out = (float*)d_out;

    uint8_t* ws = (uint8_t*)d_ws;
    uint32_t* xm = (uint32_t*)(ws);
    uint32_t* wm = (uint32_t*)(ws + XM_BYTES);
    float*    qp = (float*)(ws + XM_BYTES + WM_BYTES);

    hipLaunchKernelGGL(pack_x_k,   dim3(2048),      dim3(256), 0, stream, x, xm);
    hipLaunchKernelGGL(pack_w_k,   dim3(512),       dim3(256), 0, stream, w, wm);
    hipLaunchKernelGGL(mvm_main_k, dim3(32, 16, 8), dim3(256), 0, stream, xm, wm, qp);
    hipLaunchKernelGGL(reduce_k,   dim3(256),       dim3(256), 0, stream, qp, bias, out);
}

// Round 2
// 66.059 us; speedup vs baseline: 1.0201x; 1.0201x over previous
//
#include <hip/hip_runtime.h>
#include <stdint.h>

typedef __attribute__((ext_vector_type(4)))  int i32x4;
typedef __attribute__((ext_vector_type(16))) int i32x16;

// ws layout:
//   xq:      u16  [b=512][k=1024]                       1 MB
//   Bp:      i8   [z=8][p=2][sl=8][j=128][k=128]        2 MB
//   flags:   int  [z=8][p=2][sl=8][jblk=4]              2 KB
//   partial: f32  [z=8][b=512][j=128]                   2 MB
#define XQ_OFF 0u
#define BP_OFF 1048576u
#define FL_OFF 3145728u
#define PT_OFF 3147776u

__device__ __forceinline__ uint32_t bits2(uint32_t dw, int s){
  // dw holds two u16 (k even low, k+1 high); return bit s of each as bytes 0 and 1
  uint32_t t = dw >> s;
  return (t & 1u) | ((t >> 8) & 0x100u);
}

__global__ __launch_bounds__(256) void pack_x_k(const float* __restrict__ x, uint2* __restrict__ xq){
  int t = blockIdx.x*256 + threadIdx.x;            // 131072
  int b = t >> 8, k0 = (t & 255)*4;
  float4 v = *reinterpret_cast<const float4*>(x + b*1024 + k0);
  uint32_t u0, u1, u2, u3; float f;
  f = fminf(fmaxf(rintf(v.x*4096.f), -32768.f), 32767.f); u0 = (uint32_t)(int)f & 0xffffu;
  f = fminf(fmaxf(rintf(v.y*4096.f), -32768.f), 32767.f); u1 = (uint32_t)(int)f & 0xffffu;
  f = fminf(fmaxf(rintf(v.z*4096.f), -32768.f), 32767.f); u2 = (uint32_t)(int)f & 0xffffu;
  f = fminf(fmaxf(rintf(v.w*4096.f), -32768.f), 32767.f); u3 = (uint32_t)(int)f & 0xffffu;
  uint2 o; o.x = u0 | (u1 << 16); o.y = u2 | (u3 << 16);
  xq[t] = o;                                        // = (b*1024+k0)/4
}

__global__ __launch_bounds__(256) void pack_w_k(const float* __restrict__ w, uint32_t* __restrict__ Bw){
  int t = blockIdx.x*256 + threadIdx.x;            // 32768
  int j = t >> 8, k0 = (t & 255)*4;
  int r = k0 >> 7, kloc = k0 & 127;
  float4 v = *reinterpret_cast<const float4*>(w + j*1024 + k0);
  #pragma unroll
  for (int p = 0; p < 2; ++p){
    uint32_t q0 = (uint32_t)fminf(rintf(fmaxf(p ? -v.x : v.x, 0.f)*4096.f), 65535.f);
    uint32_t q1 = (uint32_t)fminf(rintf(fmaxf(p ? -v.y : v.y, 0.f)*4096.f), 65535.f);
    uint32_t q2 = (uint32_t)fminf(rintf(fmaxf(p ? -v.z : v.z, 0.f)*4096.f), 65535.f);
    uint32_t q3 = (uint32_t)fminf(rintf(fmaxf(p ? -v.w : v.w, 0.f)*4096.f), 65535.f);
    #pragma unroll
    for (int sl = 0; sl < 8; ++sl){
      int sh = 2*(7 - sl);
      uint32_t word = ((q0 >> sh) & 3u) | (((q1 >> sh) & 3u) << 8)
                    | (((q2 >> sh) & 3u) << 16) | (((q3 >> sh) & 3u) << 24);
      Bw[(((r*2 + p)*8 + sl)*128 + j)*32 + (kloc >> 2)] = word;
    }
  }
}

__global__ __launch_bounds__(256) void flags_k(const uint8_t* __restrict__ Bp, int* __restrict__ flags){
  int g    = blockIdx.x*4 + (threadIdx.x >> 6);    // 512 flags, one wave each
  int lane = threadIdx.x & 63;
  int jblk = g & 3;
  size_t off = (size_t)(g >> 2)*16384u + (size_t)(jblk*32 + (lane >> 1))*128u + (size_t)(lane & 1)*64u;
  const uint4* q = reinterpret_cast<const uint4*>(Bp + off);
  uint4 a = q[0], b = q[1], c = q[2], d = q[3];
  uint32_t o = a.x|a.y|a.z|a.w | b.x|b.y|b.z|b.w | c.x|c.y|c.z|c.w | d.x|d.y|d.z|d.w;
  unsigned long long m = __ballot(o != 0u);
  if (lane == 0) flags[g] = (m != 0ull) ? 1 : 0;
}

__global__ __launch_bounds__(256, 4) void mvm_main_k(const uint32_t* __restrict__ xq,
                                                     const uint8_t* __restrict__ Bp,
                                                     const int* __restrict__ flags,
                                                     float* __restrict__ partial){
  const int lane = threadIdx.x & 63;
  const int wid  = threadIdx.x >> 6;
  const int col  = lane & 31;        // output col j within j-block; also A row m = col
  const int hi   = lane >> 5;        // k-half for A/B operands
  const int z    = blockIdx.z;       // row tile r
  const int jblk = blockIdx.y;
  const int b_w  = blockIdx.x*8 + wid*2;

  // flags for this (z, jblk), all 16 (p,sl)
  int flg[16];
  #pragma unroll
  for (int i = 0; i < 16; ++i) flg[i] = flags[(z*16 + i)*4 + jblk];

  // Build A fragments from xint16: row m = col = b_loc*16 + s, k = z*128 + f*32 + hi*16 + i
  const int b_a = b_w + (col >> 4);
  const int s_a = lane & 15;
  const int kbase = z*128 + hi*16;
  const uint4* xv = reinterpret_cast<const uint4*>(xq) + (b_a*128 + (kbase >> 3));
  i32x4 afr[4];
  #pragma unroll
  for (int f = 0; f < 4; ++f){
    uint4 q0 = xv[f*4], q1 = xv[f*4 + 1];
    afr[f][0] = (int)(bits2(q0.x, s_a) | (bits2(q0.y, s_a) << 16));
    afr[f][1] = (int)(bits2(q0.z, s_a) | (bits2(q0.w, s_a) << 16));
    afr[f][2] = (int)(bits2(q1.x, s_a) | (bits2(q1.y, s_a) << 16));
    afr[f][3] = (int)(bits2(q1.z, s_a) | (bits2(q1.w, s_a) << 16));
  }

  i32x16 zz;
  #pragma unroll
  for (int i = 0; i < 16; ++i) zz[i] = 0;

  const float C1 = (float)(511.0/384.0);           // 1/ADC step
  const float QC = (float)(384.0/511.0/4096.0);    // step * 2^-24 * 4096
  float res0 = 0.f, res1 = 0.f;

  #pragma unroll
  for (int p = 0; p < 2; ++p){
    float vacc[16];
    #pragma unroll
    for (int i = 0; i < 16; ++i) vacc[i] = 0.f;

    #pragma unroll
    for (int sl = 0; sl < 8; ++sl){
      if (flg[p*8 + sl]){
        const i32x4* bp = reinterpret_cast<const i32x4*>(
            Bp + (size_t)((((z*2 + p)*8 + sl)*128) + jblk*32 + col)*128u + (size_t)(hi*16));
        i32x16 cc = zz;
        cc = __builtin_amdgcn_mfma_i32_32x32x32_i8(afr[0], bp[0], cc, 0, 0, 0);
        cc = __builtin_amdgcn_mfma_i32_32x32x32_i8(afr[1], bp[2], cc, 0, 0, 0);
        cc = __builtin_amdgcn_mfma_i32_32x32x32_i8(afr[2], bp[4], cc, 0, 0, 0);
        cc = __builtin_amdgcn_mfma_i32_32x32x32_i8(afr[3], bp[6], cc, 0, 0, 0);
        const float slw = (float)(1 << (2*(7 - sl)));
        #pragma unroll
        for (int g = 0; g < 16; ++g){
          float nf = rintf((float)cc[g] * C1);     // ADC quantization (integer-exact inputs)
          vacc[g] = fmaf(nf, slw, vacc[g]);        // exact: integers < 2^24
        }
      }
    }

    // stream shift-add: rows of C are m = b_loc*16 + s; b_loc = g>>3, s = (g&3) + 8*((g>>2)&1) + 4*hi
    float a0 = 0.f, a1 = 0.f;
    const int hv = hi*4;
    #pragma unroll
    for (int g = 0; g < 16; ++g){
      const int s_lo = (g & 3) + 8*((g >> 2) & 1);
      float wgt = (float)((1 << s_lo) << hv);      // 2^s, exact
      if (s_lo == 11) wgt = hi ? -wgt : wgt;       // s==15: two's-complement MSB negative
      if (g < 8) a0 = fmaf(vacc[g], wgt, a0);
      else       a1 = fmaf(vacc[g], wgt, a1);
    }
    a0 += __shfl_xor(a0, 32);                      // other half holds the other 8 streams
    a1 += __shfl_xor(a1, 32);

    float q0 = rintf(a0 * QC) * (1.0f/4096.0f);
    q0 = fminf(fmaxf(q0, -8.0f), 8.0f - 1.0f/4096.0f);
    float q1 = rintf(a1 * QC) * (1.0f/4096.0f);
    q1 = fminf(fmaxf(q1, -8.0f), 8.0f - 1.0f/4096.0f);
    if (p == 0){ res0 += q0; res1 += q1; } else { res0 -= q0; res1 -= q1; }
  }

  const int jout = jblk*32 + col;
  if (hi == 0) partial[(z*512 + b_w    )*128 + jout] = res0;
  else         partial[(z*512 + b_w + 1)*128 + jout] = res1;
}

__global__ __launch_bounds__(256) void reduce_k(const float* __restrict__ partial,
                                                const float* __restrict__ bias,
                                                float* __restrict__ out){
  int t = blockIdx.x*256 + threadIdx.x;            // 65536
  int b = t >> 7, j = t & 127;
  float s = 0.f;
  #pragma unroll
  for (int z = 0; z < 8; ++z) s += partial[(z*512 + b)*128 + j];  // exact multiples of 2^-12
  out[t] = s + bias[j];
}

extern "C" void kernel_launch(void* const* d_in, const int* in_sizes, int n_in,
                              void* d_out, int out_size, void* d_ws, size_t ws_size,
                              hipStream_t stream){
  const float* x    = (const float*)d_in[0];
  const float* w    = (const float*)d_in[1];
  const float* bias = (const float*)d_in[2];
  uint8_t* ws = (uint8_t*)d_ws;

  hipLaunchKernelGGL(pack_x_k, dim3(512), dim3(256), 0, stream, x, (uint2*)(ws + XQ_OFF));
  hipLaunchKernelGGL(pack_w_k, dim3(128), dim3(256), 0, stream, w, (uint32_t*)(ws + BP_OFF));
  hipLaunchKernelGGL(flags_k,  dim3(128), dim3(256), 0, stream, ws + BP_OFF, (int*)(ws + FL_OFF));
  hipLaunchKernelGGL(mvm_main_k, dim3(64, 4, 8), dim3(256), 0, stream,
                     (const uint32_t*)(ws + XQ_OFF), ws + BP_OFF,
                     (const int*)(ws + FL_OFF), (float*)(ws + PT_OFF));
  hipLaunchKernelGGL(reduce_k, dim3(256), dim3(256), 0, stream,
                     (const float*)(ws + PT_OFF), bias, (float*)d_out);
}

// Round 3
// 34.703 us; speedup vs baseline: 1.9418x; 1.9036x over previous
//
#include <hip/hip_runtime.h>
#include <stdint.h>

typedef __attribute__((ext_vector_type(4)))  int i32x4;
typedef __attribute__((ext_vector_type(16))) int i32x16;

// ws layout:
//   xq:   u16  [b=512][k=1024]                  1 MB
//   Bp:   i8   [z=8][p=2][sl=8][j=128][k=128]   2 MB
//   mask: u32  [z=8][jblk=4]                    128 B (4KB slot)
//   pt:   f32  [z=8][b=512][j=128]              2 MB
#define XQ_OFF 0u
#define BP_OFF 1048576u
#define MK_OFF 3145728u
#define PT_OFF 3149824u

// ---------------- fused input packing ----------------
__global__ __launch_bounds__(256) void pack_k(const float* __restrict__ x, const float* __restrict__ w,
                                              uint2* __restrict__ xq, uint32_t* __restrict__ Bw,
                                              uint32_t* __restrict__ mask){
  if (blockIdx.x < 512){
    // ---- x -> int16 fixed point, packed 4/thread ----
    int t = blockIdx.x*256 + threadIdx.x;            // 131072
    int b = t >> 8, k0 = (t & 255)*4;
    float4 v = *reinterpret_cast<const float4*>(x + b*1024 + k0);
    uint32_t u0, u1, u2, u3; float f;
    f = fminf(fmaxf(rintf(v.x*4096.f), -32768.f), 32767.f); u0 = (uint32_t)(int)f & 0xffffu;
    f = fminf(fmaxf(rintf(v.y*4096.f), -32768.f), 32767.f); u1 = (uint32_t)(int)f & 0xffffu;
    f = fminf(fmaxf(rintf(v.z*4096.f), -32768.f), 32767.f); u2 = (uint32_t)(int)f & 0xffffu;
    f = fminf(fmaxf(rintf(v.w*4096.f), -32768.f), 32767.f); u3 = (uint32_t)(int)f & 0xffffu;
    uint2 o; o.x = u0 | (u1 << 16); o.y = u2 | (u3 << 16);
    xq[t] = o;
  } else {
    // ---- w -> 2-bit slice planes + nonzero mask ----
    int t = (blockIdx.x - 512)*256 + threadIdx.x;    // 32768
    int j = t >> 8, kq = t & 255, k0 = kq*4;
    int r = kq >> 5, kd = kq & 31;
    float4 v = *reinterpret_cast<const float4*>(w + j*1024 + k0);
    uint32_t lm = 0;
    #pragma unroll
    for (int p = 0; p < 2; ++p){
      uint32_t q0 = (uint32_t)fminf(rintf(fmaxf(p ? -v.x : v.x, 0.f)*4096.f), 65535.f);
      uint32_t q1 = (uint32_t)fminf(rintf(fmaxf(p ? -v.y : v.y, 0.f)*4096.f), 65535.f);
      uint32_t q2 = (uint32_t)fminf(rintf(fmaxf(p ? -v.z : v.z, 0.f)*4096.f), 65535.f);
      uint32_t q3 = (uint32_t)fminf(rintf(fmaxf(p ? -v.w : v.w, 0.f)*4096.f), 65535.f);
      #pragma unroll
      for (int sl = 0; sl < 8; ++sl){
        int sh = 2*(7 - sl);
        uint32_t word = ((q0 >> sh) & 3u) | (((q1 >> sh) & 3u) << 8)
                      | (((q2 >> sh) & 3u) << 16) | (((q3 >> sh) & 3u) << 24);
        Bw[(((r*2 + p)*8 + sl)*128 + j)*32 + kd] = word;
        lm |= (word != 0u ? 1u : 0u) << (p*8 + sl);
      }
    }
    // OR-reduce within each 32-lane half (half shares same (r, jblk))
    lm |= (uint32_t)__shfl_xor((int)lm, 16);
    lm |= (uint32_t)__shfl_xor((int)lm, 8);
    lm |= (uint32_t)__shfl_xor((int)lm, 4);
    lm |= (uint32_t)__shfl_xor((int)lm, 2);
    lm |= (uint32_t)__shfl_xor((int)lm, 1);
    if ((threadIdx.x & 31) == 0) atomicOr(&mask[r*4 + (j >> 5)], lm);
  }
}

__device__ __forceinline__ uint32_t bits2(uint32_t dw, int s){
  uint32_t t = dw >> s;
  return (t & 1u) | ((t >> 8) & 0x100u);
}

// ---------------- main MFMA kernel ----------------
__global__ __launch_bounds__(512) void mvm_main_k(const uint32_t* __restrict__ xq,
                                                  const uint8_t* __restrict__ Bp,
                                                  const uint32_t* __restrict__ mask,
                                                  float* __restrict__ partial){
  __shared__ uint4 lds4[4096];                       // 16 slots x 4KB = 64KB
  uint8_t* lds = (uint8_t*)lds4;
  const int tid  = threadIdx.x;
  const int lane = tid & 63, wid = tid >> 6;         // 8 waves
  const int z = blockIdx.z, jblk = blockIdx.y;
  const int col = lane & 31, hi = lane >> 5;

  // ---- compact nonzero-tile list (uniform/scalar) ----
  const uint32_t m = mask[z*4 + jblk];
  const int n0 = __popc(m & 0xFFu);
  const int n  = __popc(m & 0xFFFFu);
  uint64_t list = 0;
  {
    uint32_t mm = m & 0xFFFFu; int cnt = 0;
    while (mm){ int idx = __ffs(mm) - 1; mm &= mm - 1; list |= (uint64_t)idx << (4*cnt); ++cnt; }
  }

  // ---- stage nonzero B tiles to LDS, XOR-swizzled (st: chunk ^= col&7) ----
  {
    const int q = lane >> 3;                         // row subgroup
    const int chunkS = (lane & 7) ^ q;               // swizzled source chunk (i-invariant)
    for (int t = wid; t < n; t += 8){
      const int idx = (int)((list >> (4*t)) & 15);
      const uint8_t* src = Bp + ((size_t)((z*16 + idx)*128 + jblk*32) << 7);
      uint4 r0 = *(const uint4*)(src + (q     )*128 + chunkS*16);
      uint4 r1 = *(const uint4*)(src + (q +  8)*128 + chunkS*16);
      uint4 r2 = *(const uint4*)(src + (q + 16)*128 + chunkS*16);
      uint4 r3 = *(const uint4*)(src + (q + 24)*128 + chunkS*16);
      uint8_t* dst = lds + t*4096 + lane*16;
      *(uint4*)(dst       ) = r0;
      *(uint4*)(dst + 1024) = r1;
      *(uint4*)(dst + 2048) = r2;
      *(uint4*)(dst + 3072) = r3;
    }
  }
  __syncthreads();

  // ---- A fragments from xint16 (validated mapping) ----
  const int b_w = blockIdx.x*16 + wid*2;
  const int b_a = b_w + (col >> 4);
  const int s_a = lane & 15;
  const uint4* xv = reinterpret_cast<const uint4*>(xq) + (b_a*128 + z*16 + hi*2);
  i32x4 afr[4];
  #pragma unroll
  for (int f = 0; f < 4; ++f){
    uint4 q0 = xv[f*4], q1 = xv[f*4 + 1];
    afr[f][0] = (int)(bits2(q0.x, s_a) | (bits2(q0.y, s_a) << 16));
    afr[f][1] = (int)(bits2(q0.z, s_a) | (bits2(q0.w, s_a) << 16));
    afr[f][2] = (int)(bits2(q1.x, s_a) | (bits2(q1.y, s_a) << 16));
    afr[f][3] = (int)(bits2(q1.z, s_a) | (bits2(q1.w, s_a) << 16));
  }

  i32x16 zz;
  #pragma unroll
  for (int i = 0; i < 16; ++i) zz[i] = 0;

  // swizzled read offsets (loop-invariant)
  const int c7 = col & 7;
  const int xo0 = ((0 + hi) ^ c7) << 4;
  const int xo1 = ((2 + hi) ^ c7) << 4;
  const int xo2 = ((4 + hi) ^ c7) << 4;
  const int xo3 = ((6 + hi) ^ c7) << 4;

  const float C1 = (float)(511.0/384.0);
  const float QC = (float)(384.0/511.0/4096.0);
  const float sc  = hi ? 16.0f : 1.0f;               // 2^(4*hi)
  const float w11 = hi ? -32768.0f : 2048.0f;        // stream 15 is negative (two's complement)
  float out0 = 0.f, out1 = 0.f;

  #pragma unroll
  for (int phase = 0; phase < 2; ++phase){
    const int tb = phase ? n0 : 0, te = phase ? n : n0;
    float vacc[16];
    #pragma unroll
    for (int g = 0; g < 16; ++g) vacc[g] = 0.f;

    for (int t = tb; t < te; ++t){
      const int sl = (int)((list >> (4*t)) & 7);
      const float slw = (float)(1 << (14 - 2*sl));   // 4^(7-sl)
      const uint8_t* lb = lds + t*4096 + col*128;
      i32x4 b0 = *(const i32x4*)(lb + xo0);
      i32x4 b1 = *(const i32x4*)(lb + xo1);
      i32x4 b2 = *(const i32x4*)(lb + xo2);
      i32x4 b3 = *(const i32x4*)(lb + xo3);
      i32x16 cc = zz;
      cc = __builtin_amdgcn_mfma_i32_32x32x32_i8(afr[0], b0, cc, 0, 0, 0);
      cc = __builtin_amdgcn_mfma_i32_32x32x32_i8(afr[1], b1, cc, 0, 0, 0);
      cc = __builtin_amdgcn_mfma_i32_32x32x32_i8(afr[2], b2, cc, 0, 0, 0);
      cc = __builtin_amdgcn_mfma_i32_32x32x32_i8(afr[3], b3, cc, 0, 0, 0);
      #pragma unroll
      for (int g = 0; g < 16; ++g)
        vacc[g] = fmaf(rintf((float)cc[g] * C1), slw, vacc[g]);  // ADC + slice shift-add (exact ints)
    }

    // stream shift-add: rows m = (g&3) + 8*((g>>2)&1) + 4*hi; s_lo = (g&3) + 8*((g>>2)&1)
    float a0 = 0.f, a1 = 0.f;
    #pragma unroll
    for (int g = 0; g < 7; ++g){
      const int s_lo = (g & 3) + 8*((g >> 2) & 1);   // 0,1,2,3,8,9,10
      a0 = fmaf(vacc[g],     (float)(1 << s_lo), a0);
      a1 = fmaf(vacc[g + 8], (float)(1 << s_lo), a1);
    }
    a0 = fmaf(vacc[7],  w11, a0*sc);                 // g=7: s_lo=11; apply 2^(4hi) + MSB sign
    a1 = fmaf(vacc[15], w11, a1*sc);
    a0 += __shfl_xor(a0, 32);                        // combine the two stream-halves
    a1 += __shfl_xor(a1, 32);

    float q0 = rintf(a0 * QC) * (1.0f/4096.0f);
    q0 = fminf(fmaxf(q0, -8.0f), 8.0f - 1.0f/4096.0f);
    float q1 = rintf(a1 * QC) * (1.0f/4096.0f);
    q1 = fminf(fmaxf(q1, -8.0f), 8.0f - 1.0f/4096.0f);
    if (phase == 0){ out0 += q0; out1 += q1; } else { out0 -= q0; out1 -= q1; }
  }

  const int jout = jblk*32 + col;
  partial[(z*512 + b_w + hi)*128 + jout] = hi ? out1 : out0;
}

__global__ __launch_bounds__(256) void reduce_k(const float* __restrict__ partial,
                                                const float* __restrict__ bias,
                                                float* __restrict__ out){
  int t = blockIdx.x*256 + threadIdx.x;              // 65536
  int b = t >> 7, j = t & 127;
  float s = 0.f;
  #pragma unroll
  for (int z = 0; z < 8; ++z) s += partial[(z*512 + b)*128 + j];  // exact multiples of 2^-12
  out[t] = s + bias[j];
}

extern "C" void kernel_launch(void* const* d_in, const int* in_sizes, int n_in,
                              void* d_out, int out_size, void* d_ws, size_t ws_size,
                              hipStream_t stream){
  const float* x    = (const float*)d_in[0];
  const float* w    = (const float*)d_in[1];
  const float* bias = (const float*)d_in[2];
  uint8_t* ws = (uint8_t*)d_ws;

  hipMemsetAsync(ws + MK_OFF, 0, 128, stream);
  hipLaunchKernelGGL(pack_k, dim3(640), dim3(256), 0, stream,
                     x, w, (uint2*)(ws + XQ_OFF), (uint32_t*)(ws + BP_OFF), (uint32_t*)(ws + MK_OFF));
  hipLaunchKernelGGL(mvm_main_k, dim3(32, 4, 8), dim3(512), 0, stream,
                     (const uint32_t*)(ws + XQ_OFF), ws + BP_OFF,
                     (const uint32_t*)(ws + MK_OFF), (float*)(ws + PT_OFF));
  hipLaunchKernelGGL(reduce_k, dim3(256), dim3(256), 0, stream,
                     (const float*)(ws + PT_OFF), bias, (float*)d_out);
}

// Round 4
// 28.069 us; speedup vs baseline: 2.4006x; 1.2363x over previous
//
#include <hip/hip_runtime.h>
#include <stdint.h>

typedef __attribute__((ext_vector_type(4)))  int i32x4;
typedef __attribute__((ext_vector_type(16))) int i32x16;

// ws layout:
//   xm: uint4 [b=512][z=8][s=16]  (4 x u32 k-bitplanes, 128 k/tile)   1 MB
//   Bp: i8    [z=8][p=2][sl=8][j=128][k=128]                          2 MB
//   pt: f32   [z=8][b=512][j=128]                                     2 MB
#define XM_OFF 0u
#define BP_OFF 1048576u
#define PT_OFF 3145728u

__device__ __forceinline__ uint32_t q16(float v){
  float f = fminf(fmaxf(rintf(v*4096.f), -32768.f), 32767.f);
  return (uint32_t)(int)f & 0xffffu;
}

// ---------- fused pack: x -> bit-planes (ballot transpose), w -> 2-bit slice planes ----------
__global__ __launch_bounds__(256) void pack_k(const float* __restrict__ x, const float* __restrict__ w,
                                              uint4* __restrict__ xm, uint32_t* __restrict__ Bw){
  const int lane = threadIdx.x & 63;
  if (blockIdx.x < 1024){
    // one wave per (b, z): transpose 128 xint16 values into 16 s-bitplanes of 4 u32
    int wv = blockIdx.x*4 + (threadIdx.x >> 6);       // 0..4095
    int b = wv >> 3, z = wv & 7;
    const float* xp = x + b*1024 + z*128;
    uint32_t u0 = q16(xp[lane]);
    uint32_t u1 = q16(xp[lane + 64]);
    uint4 out4 = {0,0,0,0};
    #pragma unroll
    for (int s = 0; s < 16; ++s){
      unsigned long long m0 = __ballot((u0 >> s) & 1u);
      unsigned long long m1 = __ballot((u1 >> s) & 1u);
      if (lane == s){
        out4.x = (uint32_t)m0; out4.y = (uint32_t)(m0 >> 32);
        out4.z = (uint32_t)m1; out4.w = (uint32_t)(m1 >> 32);
      }
    }
    if (lane < 16) xm[(b*8 + z)*16 + lane] = out4;
  } else {
    int t = (blockIdx.x - 1024)*256 + threadIdx.x;    // 32768
    int j = t >> 8, kq = t & 255;
    int r = kq >> 5, kd = kq & 31;
    float4 v = *reinterpret_cast<const float4*>(w + j*1024 + kq*4);
    #pragma unroll
    for (int p = 0; p < 2; ++p){
      uint32_t q0 = (uint32_t)fminf(rintf(fmaxf(p ? -v.x : v.x, 0.f)*4096.f), 65535.f);
      uint32_t q1 = (uint32_t)fminf(rintf(fmaxf(p ? -v.y : v.y, 0.f)*4096.f), 65535.f);
      uint32_t q2 = (uint32_t)fminf(rintf(fmaxf(p ? -v.z : v.z, 0.f)*4096.f), 65535.f);
      uint32_t q3 = (uint32_t)fminf(rintf(fmaxf(p ? -v.w : v.w, 0.f)*4096.f), 65535.f);
      #pragma unroll
      for (int sl = 0; sl < 8; ++sl){
        int sh = 2*(7 - sl);
        uint32_t word = ((q0 >> sh) & 3u) | (((q1 >> sh) & 3u) << 8)
                      | (((q2 >> sh) & 3u) << 16) | (((q3 >> sh) & 3u) << 24);
        Bw[(((r*2 + p)*8 + sl)*128 + j)*32 + kd] = word;
      }
    }
  }
}

// ---------- main MFMA kernel: static 16-tile unroll + uniform skip ----------
__global__ __launch_bounds__(512) void mvm_main_k(const uint4* __restrict__ xm,
                                                  const uint8_t* __restrict__ Bp,
                                                  float* __restrict__ partial){
  __shared__ uint8_t lds[65536];                      // 16 slots x 4KB
  __shared__ uint32_t flg[8];
  const int tid = threadIdx.x, lane = tid & 63, wid = tid >> 6;
  const int z = blockIdx.z, jblk = blockIdx.y;
  const int col = lane & 31, hi = lane >> 5;

  // ---- stage all 16 (p,sl) tiles, swizzled; record per-slot nonzero flags ----
  {
    const int q = lane >> 3, cS = (lane & 7) ^ q;
    uint32_t f2 = 0;
    #pragma unroll
    for (int u = 0; u < 2; ++u){
      const int si = wid + u*8;
      const uint8_t* src = Bp + ((size_t)((z*16 + si)*128 + jblk*32) << 7);
      uint4 r0 = *(const uint4*)(src + (q     )*128 + cS*16);
      uint4 r1 = *(const uint4*)(src + (q +  8)*128 + cS*16);
      uint4 r2 = *(const uint4*)(src + (q + 16)*128 + cS*16);
      uint4 r3 = *(const uint4*)(src + (q + 24)*128 + cS*16);
      uint8_t* dst = lds + si*4096 + lane*16;
      *(uint4*)(dst       ) = r0;
      *(uint4*)(dst + 1024) = r1;
      *(uint4*)(dst + 2048) = r2;
      *(uint4*)(dst + 3072) = r3;
      uint32_t o = r0.x|r0.y|r0.z|r0.w | r1.x|r1.y|r1.z|r1.w
                 | r2.x|r2.y|r2.z|r2.w | r3.x|r3.y|r3.z|r3.w;
      f2 |= (__any(o != 0u) ? 1u : 0u) << u;
    }
    if (lane == 0) flg[wid] = f2;
  }

  // ---- A fragments from bit-planes: 1 dwordx4 + nibble-spread (0x204081 trick) ----
  const int b_w = blockIdx.x*16 + wid*2;
  const int b_a = b_w + (col >> 4);
  const int s_a = lane & 15;
  const uint4 pw = xm[(b_a*8 + z)*16 + s_a];
  i32x4 afr[4];
  {
    const uint32_t wd[4] = {pw.x, pw.y, pw.z, pw.w};
    #pragma unroll
    for (int f = 0; f < 4; ++f){
      uint32_t pl = wd[f] >> (hi*16);
      #pragma unroll
      for (int wI = 0; wI < 4; ++wI)
        afr[f][wI] = (int)((((pl >> (wI*4)) & 0xFu) * 0x204081u) & 0x01010101u);
    }
  }
  __syncthreads();

  uint32_t msk = 0;
  #pragma unroll
  for (int w2 = 0; w2 < 8; ++w2){
    uint32_t f2 = flg[w2];
    msk |= (f2 & 1u) << w2;
    msk |= ((f2 >> 1) & 1u) << (w2 + 8);
  }
  msk = __builtin_amdgcn_readfirstlane(msk);          // force SGPR -> scalar branches

  const int c7 = col & 7;
  const int xo0 = ((0 + hi) ^ c7) << 4;
  const int xo1 = ((2 + hi) ^ c7) << 4;
  const int xo2 = ((4 + hi) ^ c7) << 4;
  const int xo3 = ((6 + hi) ^ c7) << 4;

  i32x16 zz;
  #pragma unroll
  for (int i = 0; i < 16; ++i) zz[i] = 0;

  const float C1 = (float)(511.0/384.0);
  const float QC = (float)(384.0/511.0/4096.0);
  const float sc  = hi ? 16.0f : 1.0f;                // 2^(4*hi)
  const float w11 = hi ? -32768.0f : 2048.0f;         // stream 15 negative (two's complement)
  float out0 = 0.f, out1 = 0.f;

  #pragma unroll
  for (int ph = 0; ph < 2; ++ph){
    float vacc[16];
    #pragma unroll
    for (int g = 0; g < 16; ++g) vacc[g] = 0.f;

    #pragma unroll
    for (int sl = 0; sl < 8; ++sl){
      const int ti = ph*8 + sl;
      if (msk & (1u << ti)){
        const uint8_t* lb = lds + ti*4096 + col*128;
        i32x4 b0 = *(const i32x4*)(lb + xo0);
        i32x4 b1 = *(const i32x4*)(lb + xo1);
        i32x4 b2 = *(const i32x4*)(lb + xo2);
        i32x4 b3 = *(const i32x4*)(lb + xo3);
        i32x16 cc = zz;
        cc = __builtin_amdgcn_mfma_i32_32x32x32_i8(afr[0], b0, cc, 0, 0, 0);
        cc = __builtin_amdgcn_mfma_i32_32x32x32_i8(afr[1], b1, cc, 0, 0, 0);
        cc = __builtin_amdgcn_mfma_i32_32x32x32_i8(afr[2], b2, cc, 0, 0, 0);
        cc = __builtin_amdgcn_mfma_i32_32x32x32_i8(afr[3], b3, cc, 0, 0, 0);
        const float slw = (float)(1 << (14 - 2*sl));  // 4^(7-sl)
        #pragma unroll
        for (int g = 0; g < 16; ++g)
          vacc[g] = fmaf(rintf((float)cc[g] * C1), slw, vacc[g]);  // ADC + slice shift-add
      }
    }

    // stream shift-add: s_lo = (g&3) + 8*((g>>2)&1); halves combined via lane^32
    float a0 = 0.f, a1 = 0.f;
    #pragma unroll
    for (int g = 0; g < 7; ++g){
      const int s_lo = (g & 3) + 8*((g >> 2) & 1);    // 0,1,2,3,8,9,10
      a0 = fmaf(vacc[g],     (float)(1 << s_lo), a0);
      a1 = fmaf(vacc[g + 8], (float)(1 << s_lo), a1);
    }
    a0 = fmaf(vacc[7],  w11, a0*sc);
    a1 = fmaf(vacc[15], w11, a1*sc);
    a0 += __shfl_xor(a0, 32);
    a1 += __shfl_xor(a1, 32);

    float q0 = rintf(a0 * QC) * (1.0f/4096.0f);
    q0 = fminf(fmaxf(q0, -8.0f), 8.0f - 1.0f/4096.0f);
    float q1 = rintf(a1 * QC) * (1.0f/4096.0f);
    q1 = fminf(fmaxf(q1, -8.0f), 8.0f - 1.0f/4096.0f);
    if (ph == 0){ out0 += q0; out1 += q1; } else { out0 -= q0; out1 -= q1; }
  }

  const int jout = jblk*32 + col;
  partial[(z*512 + b_w + hi)*128 + jout] = hi ? out1 : out0;
}

__global__ __launch_bounds__(256) void reduce_k(const float* __restrict__ partial,
                                                const float* __restrict__ bias,
                                                float* __restrict__ out){
  int t = blockIdx.x*256 + threadIdx.x;               // 65536
  int b = t >> 7, j = t & 127;
  float s = 0.f;
  #pragma unroll
  for (int z = 0; z < 8; ++z) s += partial[(z*512 + b)*128 + j];  // exact multiples of 2^-12
  out[t] = s + bias[j];
}

extern "C" void kernel_launch(void* const* d_in, const int* in_sizes, int n_in,
                              void* d_out, int out_size, void* d_ws, size_t ws_size,
                              hipStream_t stream){
  const float* x    = (const float*)d_in[0];
  const float* w    = (const float*)d_in[1];
  const float* bias = (const float*)d_in[2];
  uint8_t* ws = (uint8_t*)d_ws;

  hipLaunchKernelGGL(pack_k, dim3(1152), dim3(256), 0, stream,
                     x, w, (uint4*)(ws + XM_OFF), (uint32_t*)(ws + BP_OFF));
  hipLaunchKernelGGL(mvm_main_k, dim3(32, 4, 8), dim3(512), 0, stream,
                     (const uint4*)(ws + XM_OFF), ws + BP_OFF, (float*)(ws + PT_OFF));
  hipLaunchKernelGGL(reduce_k, dim3(256), dim3(256), 0, stream,
                     (const float*)(ws + PT_OFF), bias, (float*)d_out);
}